// Round 1
// baseline (128.611 us; speedup 1.0000x reference)
//
#include <hip/hip_runtime.h>
#include <hip/hip_bf16.h>

// MPS VQE: psi from MPS cores, then energy = <psi|H|psi>/<psi|psi>,
// variance = <psi|H^2|psi>/<psi|psi> - energy^2.
// H symmetric => <psi|H^2|psi> = ||H psi||^2  -> only ONE matvec needed.

#define DIM 4096
#define BOND 8
#define NMID 10

// ws layout: [0 .. 4095] float psi ; then 3 doubles: acc[0]=norm, acc[1]=psi.hpsi, acc[2]=hpsi.hpsi

// ---------------- Kernel A: build psi + norm ----------------
__global__ __launch_bounds__(256) void build_psi_kernel(
    const float* __restrict__ core0,      // (2, 8)
    const float* __restrict__ cores_mid,  // (10, 8, 2, 8)
    const float* __restrict__ core_last,  // (8, 2)
    float* __restrict__ psi_g,
    double* __restrict__ acc) {
  __shared__ float c0[16];
  __shared__ float cm[NMID * 128];
  __shared__ float cl[16];

  if (threadIdx.x < 16) {
    c0[threadIdx.x] = core0[threadIdx.x];
    cl[threadIdx.x] = core_last[threadIdx.x];
  }
  for (int j = threadIdx.x; j < NMID * 128; j += 256) cm[j] = cores_mid[j];
  __syncthreads();

  const int idx = blockIdx.x * 256 + threadIdx.x;  // 0..4095

  // bit 11 (MSB) = core0 physical index; bit (10-i) = mid core i; bit 0 = last
  float v[BOND], nv[BOND];
  const int s0 = (idx >> 11) & 1;
#pragma unroll
  for (int a = 0; a < BOND; a++) v[a] = c0[s0 * BOND + a];

#pragma unroll
  for (int i = 0; i < NMID; i++) {
    const int p = (idx >> (10 - i)) & 1;
    const float* M = &cm[i * 128 + p * BOND];  // M[a][b] at M[a*16 + b]
#pragma unroll
    for (int b = 0; b < BOND; b++) nv[b] = v[0] * M[b];
#pragma unroll
    for (int a = 1; a < BOND; a++) {
#pragma unroll
      for (int b = 0; b < BOND; b++) nv[b] += v[a] * M[a * 16 + b];
    }
#pragma unroll
    for (int a = 0; a < BOND; a++) v[a] = nv[a];
  }

  const int pl = idx & 1;
  float ps = 0.f;
#pragma unroll
  for (int a = 0; a < BOND; a++) ps += v[a] * cl[a * 2 + pl];

  psi_g[idx] = ps;

  // norm reduction: wave shuffle -> one double atomic per wave
  float sq = ps * ps;
#pragma unroll
  for (int off = 32; off > 0; off >>= 1) sq += __shfl_down(sq, off, 64);
  if ((threadIdx.x & 63) == 0) atomicAdd(&acc[0], (double)sq);
}

// ---------------- Kernel B: hpsi = H @ psi, fused dots ----------------
// One wave per row; 4 rows per 256-thread block; psi staged in LDS.
__global__ __launch_bounds__(256) void matvec_dots_kernel(
    const float* __restrict__ H,
    const float* __restrict__ psi_g,
    double* __restrict__ acc) {
  __shared__ float psi_s[DIM];
  __shared__ float wave_hpsi[4];

#pragma unroll
  for (int k = 0; k < 4; k++) {
    const int j = (k * 256 + threadIdx.x) * 4;
    *reinterpret_cast<float4*>(&psi_s[j]) =
        *reinterpret_cast<const float4*>(&psi_g[j]);
  }
  __syncthreads();

  const int wave = threadIdx.x >> 6;
  const int lane = threadIdx.x & 63;
  const int row = blockIdx.x * 4 + wave;
  const float* __restrict__ Hrow = H + (size_t)row * DIM;

  float sum = 0.f;
#pragma unroll
  for (int it = 0; it < 16; it++) {
    const int j = (it * 64 + lane) * 4;
    const float4 h = *reinterpret_cast<const float4*>(&Hrow[j]);
    const float4 p = *reinterpret_cast<const float4*>(&psi_s[j]);
    sum += h.x * p.x + h.y * p.y + h.z * p.z + h.w * p.w;
  }
#pragma unroll
  for (int off = 32; off > 0; off >>= 1) sum += __shfl_down(sum, off, 64);
  if (lane == 0) wave_hpsi[wave] = sum;
  __syncthreads();

  if (threadIdx.x == 0) {
    double ph = 0.0, hh = 0.0;
#pragma unroll
    for (int w = 0; w < 4; w++) {
      const double hp = (double)wave_hpsi[w];
      const double pr = (double)psi_s[blockIdx.x * 4 + w];
      ph += pr * hp;
      hh += hp * hp;
    }
    atomicAdd(&acc[1], ph);
    atomicAdd(&acc[2], hh);
  }
}

// ---------------- Kernel C: finalize ----------------
__global__ void finalize_kernel(const double* __restrict__ acc,
                                float* __restrict__ out) {
  const double norm = acc[0];
  const double e = acc[1] / norm;
  const double e2 = acc[2] / norm;
  double var = e2 - e * e;
  if (var < 0.0) var = 0.0;
  out[0] = (float)e;
  out[1] = (float)var;
}

extern "C" void kernel_launch(void* const* d_in, const int* in_sizes, int n_in,
                              void* d_out, int out_size, void* d_ws, size_t ws_size,
                              hipStream_t stream) {
  const float* core0 = (const float*)d_in[0];
  const float* cores_mid = (const float*)d_in[1];
  const float* core_last = (const float*)d_in[2];
  const float* H = (const float*)d_in[3];

  float* psi = (float*)d_ws;
  double* acc = (double*)((char*)d_ws + DIM * sizeof(float));

  hipMemsetAsync(acc, 0, 3 * sizeof(double), stream);
  build_psi_kernel<<<DIM / 256, 256, 0, stream>>>(core0, cores_mid, core_last, psi, acc);
  matvec_dots_kernel<<<DIM / 4, 256, 0, stream>>>(H, psi, acc);
  finalize_kernel<<<1, 1, 0, stream>>>(acc, (float*)d_out);
}

// Round 2
// 123.417 us; speedup vs baseline: 1.0421x; 1.0421x over previous
//
#include <hip/hip_runtime.h>
#include <hip/hip_bf16.h>

// MPS VQE: psi from MPS cores, then energy = <psi|H|psi>/<psi|psi>,
// variance = <psi|H^2|psi>/<psi|psi> - energy^2.
// H symmetric (bitwise: 0.5*(A+A^T)) =>
//   (1) <psi|H^2|psi> = ||H psi||^2  -> only ONE matvec needed
//   (2) SYMV tiling: read only upper-triangular 128x128 tiles (528/1024)
//       -> matvec HBM traffic 67 MB -> ~35 MB.

#define DIM 4096
#define BOND 8
#define NMID 10
#define T 128          // tile size
#define NT (DIM / T)   // 32 tiles per side
#define NPAIRS (NT * (NT + 1) / 2)  // 528 blocks

// ws layout: psi[4096] floats, hpsi[4096] floats

// ---------------- Kernel 1: build psi + zero hpsi ----------------
__global__ __launch_bounds__(256) void build_psi_kernel(
    const float* __restrict__ core0,      // (2, 8)
    const float* __restrict__ cores_mid,  // (10, 8, 2, 8)
    const float* __restrict__ core_last,  // (8, 2)
    float* __restrict__ psi_g,
    float* __restrict__ hpsi_g) {
  __shared__ float c0[16];
  __shared__ float cm[NMID * 128];
  __shared__ float cl[16];

  if (threadIdx.x < 16) {
    c0[threadIdx.x] = core0[threadIdx.x];
    cl[threadIdx.x] = core_last[threadIdx.x];
  }
  for (int j = threadIdx.x; j < NMID * 128; j += 256) cm[j] = cores_mid[j];
  __syncthreads();

  const int idx = blockIdx.x * 256 + threadIdx.x;  // 0..4095
  hpsi_g[idx] = 0.f;  // zero accumulator for the SYMV scatter (ws is poisoned)

  // bit 11 (MSB) = core0 physical index; bit (10-i) = mid core i; bit 0 = last
  float v[BOND], nv[BOND];
  const int s0 = (idx >> 11) & 1;
#pragma unroll
  for (int a = 0; a < BOND; a++) v[a] = c0[s0 * BOND + a];

#pragma unroll
  for (int i = 0; i < NMID; i++) {
    const int p = (idx >> (10 - i)) & 1;
    const float* M = &cm[i * 128 + p * BOND];  // M[a][b] at M[a*16 + b]
#pragma unroll
    for (int b = 0; b < BOND; b++) nv[b] = v[0] * M[b];
#pragma unroll
    for (int a = 1; a < BOND; a++) {
#pragma unroll
      for (int b = 0; b < BOND; b++) nv[b] += v[a] * M[a * 16 + b];
    }
#pragma unroll
    for (int a = 0; a < BOND; a++) v[a] = nv[a];
  }

  const int pl = idx & 1;
  float ps = 0.f;
#pragma unroll
  for (int a = 0; a < BOND; a++) ps += v[a] * cl[a * 2 + pl];

  psi_g[idx] = ps;
}

// ---------------- Kernel 2: symmetric matvec (upper-tri tiles only) -------
// Block b -> tile (bi, bj), bi <= bj. One read of A_IJ feeds both
// yI += A_IJ * xJ (row dots) and yJ += A_IJ^T * xI (per-lane accumulators).
__global__ __launch_bounds__(256) void symv_kernel(
    const float* __restrict__ H,
    const float* __restrict__ psi_g,
    float* __restrict__ hpsi_g) {
  // linear triangular index -> (bi, bj)
  int rem = blockIdx.x;
  int bi = 0;
  while (rem >= NT - bi) { rem -= (NT - bi); ++bi; }
  const int bj = bi + rem;
  const bool diag = (bi == bj);

  __shared__ float xI[T], xJ[T], yI_s[T], yJp[4 * T];

  if (threadIdx.x < T) {
    xI[threadIdx.x] = psi_g[bi * T + threadIdx.x];
    xJ[threadIdx.x] = psi_g[bj * T + threadIdx.x];
  }
  __syncthreads();

  const int wave = threadIdx.x >> 6;
  const int lane = threadIdx.x & 63;
  const float* __restrict__ base = H + (size_t)(bi * T) * DIM + bj * T;

  float aJx = 0.f, aJy = 0.f;
  const float pJx = xJ[lane * 2], pJy = xJ[lane * 2 + 1];

#pragma unroll 4
  for (int k = 0; k < T / 4; ++k) {
    const int r = k * 4 + wave;  // rows partitioned across the 4 waves
    const float2 a = *reinterpret_cast<const float2*>(base + (size_t)r * DIM + lane * 2);
    const float xr = xI[r];
    aJx += a.x * xr;
    aJy += a.y * xr;
    float d = a.x * pJx + a.y * pJy;
#pragma unroll
    for (int off = 32; off > 0; off >>= 1) d += __shfl_down(d, off, 64);
    if (lane == 0) yI_s[r] = d;
  }

  yJp[wave * T + lane * 2] = aJx;
  yJp[wave * T + lane * 2 + 1] = aJy;
  __syncthreads();

  if (threadIdx.x < T) {
    atomicAdd(&hpsi_g[bi * T + threadIdx.x], yI_s[threadIdx.x]);
    if (!diag) {
      const float yj = yJp[threadIdx.x] + yJp[T + threadIdx.x] +
                       yJp[2 * T + threadIdx.x] + yJp[3 * T + threadIdx.x];
      atomicAdd(&hpsi_g[bj * T + threadIdx.x], yj);
    }
  }
}

// ---------------- Kernel 3: the three dots + finalize (single block) -------
__global__ __launch_bounds__(256) void dots_kernel(
    const float* __restrict__ psi_g,
    const float* __restrict__ hpsi_g,
    float* __restrict__ out) {
  __shared__ double s_n[4], s_ph[4], s_hh[4];
  double n = 0.0, ph = 0.0, hh = 0.0;
  for (int i = threadIdx.x; i < DIM; i += 256) {
    const double p = (double)psi_g[i];
    const double h = (double)hpsi_g[i];
    n += p * p;
    ph += p * h;
    hh += h * h;
  }
#pragma unroll
  for (int off = 32; off > 0; off >>= 1) {
    n += __shfl_down(n, off, 64);
    ph += __shfl_down(ph, off, 64);
    hh += __shfl_down(hh, off, 64);
  }
  const int wave = threadIdx.x >> 6;
  const int lane = threadIdx.x & 63;
  if (lane == 0) { s_n[wave] = n; s_ph[wave] = ph; s_hh[wave] = hh; }
  __syncthreads();
  if (threadIdx.x == 0) {
    double N = 0.0, P = 0.0, HH = 0.0;
#pragma unroll
    for (int w = 0; w < 4; w++) { N += s_n[w]; P += s_ph[w]; HH += s_hh[w]; }
    const double e = P / N;
    const double e2 = HH / N;
    double var = e2 - e * e;
    if (var < 0.0) var = 0.0;
    out[0] = (float)e;
    out[1] = (float)var;
  }
}

extern "C" void kernel_launch(void* const* d_in, const int* in_sizes, int n_in,
                              void* d_out, int out_size, void* d_ws, size_t ws_size,
                              hipStream_t stream) {
  const float* core0 = (const float*)d_in[0];
  const float* cores_mid = (const float*)d_in[1];
  const float* core_last = (const float*)d_in[2];
  const float* H = (const float*)d_in[3];

  float* psi = (float*)d_ws;
  float* hpsi = psi + DIM;

  build_psi_kernel<<<DIM / 256, 256, 0, stream>>>(core0, cores_mid, core_last, psi, hpsi);
  symv_kernel<<<NPAIRS, 256, 0, stream>>>(H, psi, hpsi);
  dots_kernel<<<1, 256, 0, stream>>>(psi, hpsi, (float*)d_out);
}